// Round 15
// baseline (201.166 us; speedup 1.0000x reference)
//
#include <hip/hip_runtime.h>
#include <string.h>

#define Dims 256
#define BM 32
#define BN 32
#define KC 128
#define NSEG 16
#define BIAS 2048.0f
// interleave: groups of (RMD+RCP) blocks = RMD mdist + RCP copy
#define RMD 4
#define RCP 1

typedef float f32x4 __attribute__((ext_vector_type(4)));

// ---------- Threefry2x32 (JAX), usable host+device ----------
__host__ __device__ inline void tf2x32(unsigned k0, unsigned k1,
                                       unsigned x0, unsigned x1,
                                       unsigned* o0, unsigned* o1) {
  unsigned ks[3] = {k0, k1, k0 ^ k1 ^ 0x1BD11BDAu};
  x0 += ks[0]; x1 += ks[1];
  const unsigned rA[4] = {13u, 15u, 26u, 6u};
  const unsigned rB[4] = {17u, 29u, 16u, 24u};
#pragma unroll
  for (int g = 0; g < 5; ++g) {
    const unsigned* rr = (g & 1) ? rB : rA;
#pragma unroll
    for (int j = 0; j < 4; ++j) {
      x0 += x1;
      x1 = (x1 << rr[j]) | (x1 >> (32u - rr[j]));
      x1 ^= x0;
    }
    x0 += ks[(g + 1) % 3];
    x1 += ks[(g + 2) % 3] + (unsigned)(g + 1);
  }
  *o0 = x0; *o1 = x1;
}

// f32 -> fp8 e4m3fn (RNE, saturate, flush small to 0)
__device__ inline unsigned f2e4m3(float f) {
  unsigned u = __builtin_bit_cast(unsigned, f);
  unsigned s = (u >> 24) & 0x80u;
  int e = (int)((u >> 23) & 0xFFu) - 127;
  unsigned m = u & 0x7FFFFFu;
  if (e < -6) return s;
  unsigned mr = m + 0x7FFFFu + ((m >> 20) & 1u);
  unsigned mm;
  if (mr & 0x800000u) { mm = 0u; e += 1; } else mm = mr >> 20;
  if (e > 8) return s | 0x7Eu;
  return s | ((unsigned)(e + 7) << 3) | mm;
}

// ---------- 1a) parallel count: 64 blocks over idx_train ----------
__global__ __launch_bounds__(256) void k_count(
    const int* __restrict__ idx_train, const int* __restrict__ y, int NT,
    int ept, int* __restrict__ cnt1, int* __restrict__ cnt0) {
  int t = threadIdx.x, b = blockIdx.x;
  int base = (b * 256 + t) * ept;
  int n1 = 0, n0 = 0;
  for (int k = 0; k < ept; ++k) {
    int e = base + k;
    if (e < NT) {
      if (y[idx_train[e]] == 1) n1++; else n0++;
    }
  }
  int lane = t & 63, w = t >> 6;
#pragma unroll
  for (int d = 32; d >= 1; d >>= 1) {
    n1 += __shfl_down(n1, d, 64);
    n0 += __shfl_down(n0, d, 64);
  }
  __shared__ int s1[4], s0[4];
  if (lane == 0) { s1[w] = n1; s0[w] = n0; }
  __syncthreads();
  if (t == 0) {
    cnt1[b] = s1[0] + s1[1] + s1[2] + s1[3];
    cnt0[b] = s0[0] + s0[1] + s0[2] + s0[3];
  }
}

// ---------- 1b) stable scatter into chosen/benign ----------
__global__ __launch_bounds__(256) void k_scatter(
    const int* __restrict__ idx_train, const int* __restrict__ y, int NT,
    int ept, const int* __restrict__ cnt1, const int* __restrict__ cnt0,
    int* __restrict__ chosen, int* __restrict__ benign) {
  int t = threadIdx.x, b = blockIdx.x;
  int base1 = 0, base0 = 0;
  for (int i = 0; i < b; ++i) { base1 += cnt1[i]; base0 += cnt0[i]; }
  int base = (b * 256 + t) * ept;
  int n1 = 0, n0 = 0;
  for (int k = 0; k < ept; ++k) {
    int e = base + k;
    if (e < NT) {
      if (y[idx_train[e]] == 1) n1++; else n0++;
    }
  }
  int lane = t & 63, w = t >> 6;
  int s1v = n1, s0v = n0;
#pragma unroll
  for (int d = 1; d < 64; d <<= 1) {
    int v1 = __shfl_up(s1v, d, 64);
    int v0 = __shfl_up(s0v, d, 64);
    if (lane >= d) { s1v += v1; s0v += v0; }
  }
  __shared__ int wsum1[4], wsum0[4], woff1[4], woff0[4];
  if (lane == 63) { wsum1[w] = s1v; wsum0[w] = s0v; }
  __syncthreads();
  if (t == 0) {
    int a = 0, c = 0;
    for (int i = 0; i < 4; ++i) {
      woff1[i] = a; a += wsum1[i];
      woff0[i] = c; c += wsum0[i];
    }
  }
  __syncthreads();
  int p1 = base1 + woff1[w] + s1v - n1;
  int p0 = base0 + woff0[w] + s0v - n0;
  for (int k = 0; k < ept; ++k) {
    int e = base + k;
    if (e < NT) {
      int idx = idx_train[e];
      if (y[idx] == 1) chosen[p1++] = idx; else benign[p0++] = idx;
    }
  }
}

// ---------- 2) fused sample + gather + fp8 convert + norms + key init ----------
__global__ __launch_bounds__(256) void k_prep(
    const float* __restrict__ x, const int* __restrict__ chosen,
    const int* __restrict__ benign, int n, int ncap,
    unsigned span, unsigned k1a, unsigned k1b, unsigned k2a, unsigned k2b,
    unsigned mult, unsigned char* __restrict__ Cb, unsigned char* __restrict__ Bb,
    int* __restrict__ brow, float* __restrict__ normb,
    unsigned* __restrict__ packed) {
  int g = blockIdx.x * 4 + (threadIdx.x >> 6);
  int lane = threadIdx.x & 63;
  bool isC = (g < ncap);
  int j = isC ? g : (g - ncap);
  if (isC && lane == 0) packed[j] = 0xFFFFFFFFu;
  unsigned char* dst = (isC ? Cb : Bb) + ((size_t)j << 8) + lane * 4;
  if (j >= n) {
    *(unsigned*)dst = 0u;
    if (!isC && lane == 0) normb[j] = 3.4e38f;
    return;
  }
  int row;
  if (isC) {
    row = chosen[j];
  } else {
    unsigned a0, a1, b0, b1;
    tf2x32(k1a, k1b, 0u, (unsigned)j, &a0, &a1);
    tf2x32(k2a, k2b, 0u, (unsigned)j, &b0, &b1);
    unsigned hi = a0 ^ a1, lo = b0 ^ b1;
    unsigned r = ((hi % span) * mult + (lo % span)) % span;
    row = benign[r];
    if (lane == 0) brow[j] = row;
  }
  float4 v = ((const float4*)(x + ((size_t)row << 8)))[lane];
  unsigned p = f2e4m3(v.x) | (f2e4m3(v.y) << 8) | (f2e4m3(v.z) << 16) |
               (f2e4m3(v.w) << 24);
  *(unsigned*)dst = p;
  if (!isC) {
    float s = v.x * v.x + v.y * v.y + v.z * v.z + v.w * v.w;
#pragma unroll
    for (int m = 32; m >= 1; m >>= 1) s += __shfl_xor(s, m, 64);
    if (lane == 0) normb[j] = s;
  }
}

// ---------- 3) fused: fp8 MFMA distance+argmin + x-copy/tails, RMD:RCP interleaved ----------
// R13 proved the interleave (-28us); R15 retunes ratio 4:3 -> 4:1 (R14 intent;
// R14 failed compile: __builtin_nontemporal_* rejects HIP float4 -> use
// ext_vector f32x4 on the copy path). Mechanism: HBM-bound copy saturates at
// ~512 blocks; extra copy blocks stole CU wave-slots from latency-bound mdist.
// launch_bounds stays (256,2): raising min-blocks clamps VGPR and spills (R8/R9).
__global__ __launch_bounds__(256, 2) void k_main(
    const unsigned char* __restrict__ Cb, const unsigned char* __restrict__ Bb,
    const float* __restrict__ normb, const float* __restrict__ x,
    const int* __restrict__ y, const int* __restrict__ idx_train,
    int n, int ncap, int nbmd, int N, int NT,
    unsigned* __restrict__ packed, float* __restrict__ out) {
  const int gg = blockIdx.x / (RMD + RCP), rg = blockIdx.x % (RMD + RCP);
  if (rg >= RMD) {
    // ---- copy part: x -> out, plus y/idx tails (non-temporal) ----
    const int cid = gg * RCP + (rg - RMD);
    const int ncb = (gridDim.x / (RMD + RCP)) * RCP;
    const size_t stride = (size_t)ncb * 256;
    const size_t total4 = (size_t)N * 64;
    const f32x4* __restrict__ x4 = (const f32x4*)x;
    f32x4* __restrict__ o4 = (f32x4*)out;
    for (size_t i = (size_t)cid * 256 + threadIdx.x; i < total4; i += stride) {
      f32x4 v = __builtin_nontemporal_load(&x4[i]);
      __builtin_nontemporal_store(v, &o4[i]);
    }
    long base2 = (long)(N + n) * Dims;
    long base3 = base2 + (N + n);
    long start = (long)cid * 256 + threadIdx.x;
    for (long k = start; k < N + n; k += stride)
      out[base2 + k] = (k < N) ? (float)y[k] : 1.0f;
    for (long k = start; k < NT + n; k += stride)
      out[base3 + k] = (k < NT) ? (float)idx_train[k] : (float)(N + (k - NT));
    return;
  }
  const int mb = gg * RMD + rg;
  if (mb >= nbmd) return;
  __shared__ __align__(16) char Bs[2][16384];
  const int tid = threadIdx.x;
  const int l = tid & 63;
  const int w = tid >> 6;
  const int lr = l & 15, lg = l >> 4;
  const int seg = mb & (NSEG - 1);       // B-segment (L2 locality per XCD)
  const int R0 = (mb / NSEG) * 128;      // 128-row blocks (wave = 32 rows)
  const int ntiles = ncap >> 6;
  const int per = (ntiles + NSEG - 1) / NSEG;
  const int t0 = seg * per;
  int t1 = t0 + per; if (t1 > ntiles) t1 = ntiles;
  if (t0 >= t1) return;

  // staging: thread owns col sc(+32), 8B chunks sq+8i
  const int sc = tid >> 3;
  const int sq = tid & 7;
  const int sqm = sq | ((sq & 1) << 3);    // f(c) for c=sq+8i (i-independent)
  const int lgm = lg | ((lg & 1) << 3);    // f(c) lane part for reads

  long sreg[4];
#define SLOADH(ct, half)                                                        \
  {                                                                             \
    const char* sb = (const char*)Bb + ((size_t)(ct) << 14) +                   \
                     (size_t)(sc + (half) * 32) * 256 + sq * 8;                 \
    _Pragma("unroll") for (int i = 0; i < 4; ++i)                               \
        sreg[i] = *(const long*)(sb + i * 64);                                  \
  }
#define SWRITEH(buf, half)                                                      \
  {                                                                             \
    char* db = Bs[buf];                                                         \
    const int colh = sc + (half) * 32;                                          \
    _Pragma("unroll") for (int i = 0; i < 4; ++i) {                             \
      const int c = sq + 8 * i;                                                 \
      const int S = ((colh >> 4) * 8 + (c >> 2)) * 64 + (c & 3) * 16 +          \
                    (colh & 15);                                                \
      *(long*)(db + ((S ^ sqm) << 3)) = sreg[i];                                \
    }                                                                           \
  }

  // prologue: stage tile t0; pull A fragments (fp8, 8B each) into regs
  SLOADH(t0, 0);
  long af[2][8];
  {
    const char* Ab = (const char*)Cb + (size_t)(R0 + w * 32 + lr) * 256 + lg * 8;
#pragma unroll
    for (int mf = 0; mf < 2; ++mf)
#pragma unroll
      for (int ko = 0; ko < 8; ++ko)
        af[mf][ko] = *(const long*)(Ab + mf * 4096 + ko * 32);
  }
  SWRITEH(0, 0);
  SLOADH(t0, 1);
  SWRITEH(0, 1);
  __syncthreads();

  unsigned key[2][4];
#pragma unroll
  for (int mf = 0; mf < 2; ++mf)
#pragma unroll
    for (int j = 0; j < 4; ++j) key[mf][j] = 0xFFFFFFFFu;

  const int rowbase = R0 + w * 32 + lg * 4;  // + mf*16 + j

  int cur = 0;
  for (int ct = t0; ct < t1; ++ct) {
    const int C0 = ct << 6;
    const bool more = (ct + 1 < t1);
    const int nxt = cur ^ 1;

    if (more) SLOADH(ct + 1, 0);   // issued first: SWRITEH waits vmcnt(4), nb stays in flight
    float nb[4];
#pragma unroll
    for (int nf = 0; nf < 4; ++nf) nb[nf] = normb[C0 + nf * 16 + lr] + BIAS;

    f32x4 acc[2][4];
#pragma unroll
    for (int mf = 0; mf < 2; ++mf)
#pragma unroll
      for (int nf = 0; nf < 4; ++nf) acc[mf][nf] = (f32x4){0.f, 0.f, 0.f, 0.f};

    const char* Bbuf = Bs[cur];
#pragma unroll
    for (int ko = 0; ko < 4; ++ko) {
      long bf[4];
#pragma unroll
      for (int nf = 0; nf < 4; ++nf)
        bf[nf] = *(const long*)(Bbuf +
            (((nf * 8 + ko) * 64 + lg * 16 + (lr ^ lgm ^ ((ko & 1) << 2))) << 3));
      __builtin_amdgcn_s_setprio(1);
#pragma unroll
      for (int mf = 0; mf < 2; ++mf)
#pragma unroll
        for (int nf = 0; nf < 4; ++nf)
          acc[mf][nf] = __builtin_amdgcn_mfma_f32_16x16x32_fp8_fp8(
              af[mf][ko], bf[nf], acc[mf][nf], 0, 0, 0);
      __builtin_amdgcn_s_setprio(0);
    }
    if (more) {
      SWRITEH(nxt, 0);
      SLOADH(ct + 1, 1);
    }
#pragma unroll
    for (int ko = 4; ko < 8; ++ko) {
      long bf[4];
#pragma unroll
      for (int nf = 0; nf < 4; ++nf)
        bf[nf] = *(const long*)(Bbuf +
            (((nf * 8 + ko) * 64 + lg * 16 + (lr ^ lgm ^ ((ko & 1) << 2))) << 3));
      __builtin_amdgcn_s_setprio(1);
#pragma unroll
      for (int mf = 0; mf < 2; ++mf)
#pragma unroll
        for (int nf = 0; nf < 4; ++nf)
          acc[mf][nf] = __builtin_amdgcn_mfma_f32_16x16x32_fp8_fp8(
              af[mf][ko], bf[nf], acc[mf][nf], 0, 0, 0);
      __builtin_amdgcn_s_setprio(0);
    }

    // epilogue: m = nb + BIAS - 2*dot (row norm dropped: argmin-invariant)
    const bool ovl = (R0 + 128 > C0) && (R0 < C0 + 64);
#pragma unroll
    for (int mf = 0; mf < 2; ++mf) {
#pragma unroll
      for (int j = 0; j < 4; ++j) {
        unsigned kmin = key[mf][j];
        const int rowg = rowbase + mf * 16 + j;
#pragma unroll
        for (int nf = 0; nf < 4; ++nf) {
          const int colg = C0 + nf * 16 + lr;
          float m = fmaf(acc[mf][nf][j], -2.0f, nb[nf]);
          unsigned q = (__builtin_bit_cast(unsigned, m) & 0xFFFFC000u) | (unsigned)colg;
          if (ovl && colg == rowg) q = 0xFFFFFFFFu;
          kmin = (q < kmin) ? q : kmin;
        }
        key[mf][j] = kmin;
      }
    }

    if (more) {
      SWRITEH(nxt, 1);
      __syncthreads();
      cur = nxt;
    }
  }
#undef SLOADH
#undef SWRITEH

#pragma unroll
  for (int mf = 0; mf < 2; ++mf) {
#pragma unroll
    for (int j = 0; j < 4; ++j) {
      unsigned k = key[mf][j];
#pragma unroll
      for (int m = 1; m < 16; m <<= 1) {
        unsigned o = __shfl_xor(k, m, 64);
        k = (o < k) ? o : k;
      }
      if (lr == 0) {
        int rowg = rowbase + mf * 16 + j;
        if (rowg < n) atomicMin(&packed[rowg], k);
      }
    }
  }
}

// ---------- 4) interpolated synthetic rows ----------
__global__ __launch_bounds__(256) void k_final(
    const float* __restrict__ x, const int* __restrict__ crow,
    const int* __restrict__ brow, const unsigned* __restrict__ packed,
    int N, int n, float interp, float* __restrict__ out) {
  int r = blockIdx.x * 4 + (threadIdx.x >> 6);
  int lane = threadIdx.x & 63;
  if (r >= n) return;
  int col = (int)(packed[r] & 0x3FFFu);
  const float4* c = (const float4*)(x + ((size_t)crow[r] << 8));
  const float4* b = (const float4*)(x + ((size_t)brow[col] << 8));
  float4 cv = c[lane], bv = b[lane];
  float4 o;
  o.x = cv.x + (bv.x - cv.x) * interp;
  o.y = cv.y + (bv.y - cv.y) * interp;
  o.z = cv.z + (bv.z - cv.z) * interp;
  o.w = cv.w + (bv.w - cv.w) * interp;
  ((float4*)(out + ((size_t)N + r) * Dims))[lane] = o;
}

// ---------- standalone copy (fallback path) ----------
__global__ __launch_bounds__(256) void k_copy(
    const float* __restrict__ x, const int* __restrict__ y,
    const int* __restrict__ idx_train, int N, int NT, int n,
    float* __restrict__ out) {
  const size_t total4 = (size_t)N * 64;
  const size_t stride = (size_t)gridDim.x * 256;
  const float4* __restrict__ x4 = (const float4*)x;
  float4* __restrict__ o4 = (float4*)out;
  for (size_t i = (size_t)blockIdx.x * 256 + threadIdx.x; i < total4; i += stride)
    o4[i] = x4[i];
  long base2 = (long)(N + n) * Dims;
  long base3 = base2 + (N + n);
  long start = (long)blockIdx.x * 256 + threadIdx.x;
  for (long k = start; k < N + n; k += stride)
    out[base2 + k] = (k < N) ? (float)y[k] : 1.0f;
  for (long k = start; k < NT + n; k += stride)
    out[base3 + k] = (k < NT) ? (float)idx_train[k] : (float)(N + (k - NT));
}

// ---------- fallback fp32 path ----------
__global__ void k_sample(const int* __restrict__ benign, int n, unsigned span,
                         unsigned k1a, unsigned k1b, unsigned k2a, unsigned k2b,
                         unsigned mult, int* __restrict__ brow) {
  int j = blockIdx.x * blockDim.x + threadIdx.x;
  if (j >= n) return;
  unsigned a0, a1, b0, b1;
  tf2x32(k1a, k1b, 0u, (unsigned)j, &a0, &a1);
  tf2x32(k2a, k2b, 0u, (unsigned)j, &b0, &b1);
  unsigned hi = a0 ^ a1, lo = b0 ^ b1;
  unsigned r = ((hi % span) * mult + (lo % span)) % span;
  brow[j] = benign[r];
}

__global__ __launch_bounds__(64) void k_norms(
    const float* __restrict__ x, const int* __restrict__ crow,
    const int* __restrict__ brow, int n, int ncap, float* __restrict__ normc,
    float* __restrict__ normb) {
  int b = blockIdx.x;
  int lane = threadIdx.x;
  bool isC = (b < ncap);
  int j = isC ? b : (b - ncap);
  if (j >= n) {
    if (lane == 0) { if (isC) normc[j] = 0.f; else normb[j] = 3.4e38f; }
    return;
  }
  int row = isC ? crow[j] : brow[j];
  float4 v = ((const float4*)(x + ((size_t)row << 8)))[lane];
  float s = v.x * v.x + v.y * v.y + v.z * v.z + v.w * v.w;
#pragma unroll
  for (int m = 32; m >= 1; m >>= 1) s += __shfl_xor(s, m, 64);
  if (lane == 0) { if (isC) normc[j] = s; else normb[j] = s; }
}

__global__ __launch_bounds__(256) void k_dist(
    const float* __restrict__ x, const int* __restrict__ crow,
    const int* __restrict__ brow, const float* __restrict__ normc,
    const float* __restrict__ normb, int n, int* __restrict__ neigh) {
  __shared__ float cs[BM][Dims + 4];
  __shared__ float bs[BN][KC + 4];
  const int tid = threadIdx.x;
  const int tx = tid & 15, ty = tid >> 4;
  const int R0 = blockIdx.x * BM;
  const int gra = R0 + ty, grb = R0 + ty + 16;
  for (int k = tid; k < BM * (Dims / 4); k += 256) {
    int r = k >> 6, i4 = k & 63;
    int gr = R0 + r;
    float4 v = make_float4(0.f, 0.f, 0.f, 0.f);
    if (gr < n) v = *(const float4*)(x + (size_t)crow[gr] * Dims + i4 * 4);
    *(float4*)(&cs[r][i4 * 4]) = v;
  }
  float nca = 0.f, ncb = 0.f;
  if (gra < n) nca = normc[gra];
  if (grb < n) ncb = normc[grb];
  float bva = 3.4e38f, bvb = 3.4e38f;
  int bia = 0, bib = 0;
  for (int C0 = 0; C0 < n; C0 += BN) {
    float a00 = 0.f, a01 = 0.f, a10 = 0.f, a11 = 0.f;
    for (int k0 = 0; k0 < Dims; k0 += KC) {
      __syncthreads();
      for (int k = tid; k < BN * (KC / 4); k += 256) {
        int c = k >> 5, i4 = k & 31;
        int gc = C0 + c;
        float4 v = make_float4(0.f, 0.f, 0.f, 0.f);
        if (gc < n) v = *(const float4*)(x + (size_t)brow[gc] * Dims + k0 + i4 * 4);
        *(float4*)(&bs[c][i4 * 4]) = v;
      }
      __syncthreads();
#pragma unroll 8
      for (int i = 0; i < KC; i += 4) {
        float4 ca = *(const float4*)(&cs[ty][k0 + i]);
        float4 cb = *(const float4*)(&cs[ty + 16][k0 + i]);
        float4 ba = *(const float4*)(&bs[tx][i]);
        float4 bb = *(const float4*)(&bs[tx + 16][i]);
        a00 += ca.x * ba.x + ca.y * ba.y + ca.z * ba.z + ca.w * ba.w;
        a01 += ca.x * bb.x + ca.y * bb.y + ca.z * bb.z + ca.w * bb.w;
        a10 += cb.x * ba.x + cb.y * ba.y + cb.z * ba.z + cb.w * ba.w;
        a11 += cb.x * bb.x + cb.y * bb.y + cb.z * bb.z + cb.w * bb.w;
      }
    }
    int gca = C0 + tx, gcb = C0 + tx + 16;
    if (gca < n) {
      float nbv = normb[gca];
      if (gra < n && gca != gra) {
        float d2 = nca + nbv - 2.f * a00;
        if (d2 < bva) { bva = d2; bia = gca; }
      }
      if (grb < n && gca != grb) {
        float d2 = ncb + nbv - 2.f * a10;
        if (d2 < bvb) { bvb = d2; bib = gca; }
      }
    }
    if (gcb < n) {
      float nbv = normb[gcb];
      if (gra < n && gcb != gra) {
        float d2 = nca + nbv - 2.f * a01;
        if (d2 < bva) { bva = d2; bia = gcb; }
      }
      if (grb < n && gcb != grb) {
        float d2 = ncb + nbv - 2.f * a11;
        if (d2 < bvb) { bvb = d2; bib = gcb; }
      }
    }
  }
#pragma unroll
  for (int m = 1; m < 16; m <<= 1) {
    float ov = __shfl_xor(bva, m, 64);
    int oi = __shfl_xor(bia, m, 64);
    if (ov < bva || (ov == bva && oi < bia)) { bva = ov; bia = oi; }
    ov = __shfl_xor(bvb, m, 64);
    oi = __shfl_xor(bib, m, 64);
    if (ov < bvb || (ov == bvb && oi < bib)) { bvb = ov; bib = oi; }
  }
  if (tx == 0) {
    if (gra < n) neigh[gra] = bia;
    if (grb < n) neigh[grb] = bib;
  }
}

__global__ __launch_bounds__(64) void k_newembed_int(
    const float* __restrict__ x, const int* __restrict__ crow,
    const int* __restrict__ brow, const int* __restrict__ neigh,
    int N, float interp, float* __restrict__ out) {
  int r = blockIdx.x;
  int lane = threadIdx.x;
  const float4* c = (const float4*)(x + (size_t)crow[r] * Dims);
  const float4* b = (const float4*)(x + (size_t)brow[neigh[r]] * Dims);
  float4 cv = c[lane], bv = b[lane];
  float4 o;
  o.x = cv.x + (bv.x - cv.x) * interp;
  o.y = cv.y + (bv.y - cv.y) * interp;
  o.z = cv.z + (bv.z - cv.z) * interp;
  o.w = cv.w + (bv.w - cv.w) * interp;
  ((float4*)(out + ((size_t)N + r) * Dims))[lane] = o;
}

extern "C" void kernel_launch(void* const* d_in, const int* in_sizes, int n_in,
                              void* d_out, int out_size, void* d_ws, size_t ws_size,
                              hipStream_t stream) {
  const float* x = (const float*)d_in[0];
  const int* y = (const int*)d_in[1];
  const int* idx_train = (const int*)d_in[2];
  float* out = (float*)d_out;
  const int N = in_sizes[1];
  const int NT = in_sizes[2];

  long nl = ((long)out_size - ((long)N * Dims + N + NT)) / (Dims + 2);
  int n = (int)nl;
  if (n < 0) n = 0;
  if (n > NT) n = NT;
  int nb = NT - n;
  int ncap = (n + 255) & ~255;
  if (ncap < 256) ncap = 256;

  size_t cap = ((size_t)NT + 255) & ~(size_t)255;
  int* chosen = (int*)d_ws;
  int* benign = chosen + cap;
  int* brow = benign + cap;
  int* neigh = brow + cap;
  float* normc = (float*)(neigh + cap);
  float* normb = normc + cap;
  unsigned* packed = (unsigned*)(normb + cap);
  unsigned char* Cb = (unsigned char*)(packed + ((ncap + 255) & ~255));
  unsigned char* Bb = Cb + (size_t)ncap * 256;
  size_t need = (char*)(Bb + (size_t)ncap * 256) - (char*)d_ws;
  bool use_mfma = (ws_size >= need) && (ncap <= 16384);
  int* cnt1 = neigh;
  int* cnt0 = neigh + 64;

  // Host-side JAX threefry derivations from key(42)
  unsigned s0_, s1_, t0_, t1_;
  tf2x32(0u, 42u, 0u, 0u, &s0_, &s1_);
  tf2x32(0u, 42u, 0u, 1u, &t0_, &t1_);
  unsigned i0_, i1_;
  tf2x32(t0_, t1_, 0u, 0u, &i0_, &i1_);
  unsigned ub = i0_ ^ i1_;
  float interp;
  { unsigned uu = (ub >> 9) | 0x3f800000u; memcpy(&interp, &uu, 4); interp -= 1.0f; }
  unsigned k1a, k1b, k2a, k2b;
  { unsigned a, b; tf2x32(s0_, s1_, 0u, 0u, &a, &b); k1a = a; k1b = b; }
  { unsigned a, b; tf2x32(s0_, s1_, 0u, 1u, &a, &b); k2a = a; k2b = b; }
  unsigned span = (nb > 0) ? (unsigned)nb : 1u;
  unsigned m0 = 65536u % span;
  unsigned mult = (m0 * m0) % span;

  int ept = (NT + 64 * 256 - 1) / (64 * 256);
  k_count<<<64, 256, 0, stream>>>(idx_train, y, NT, ept, cnt1, cnt0);
  k_scatter<<<64, 256, 0, stream>>>(idx_train, y, NT, ept, cnt1, cnt0, chosen, benign);
  if (n > 0 && nb > 0) {
    if (use_mfma) {
      k_prep<<<(2 * ncap) / 4, 256, 0, stream>>>(x, chosen, benign, n, ncap, span,
                                                 k1a, k1b, k2a, k2b, mult,
                                                 Cb, Bb, brow, normb, packed);
      int nrb = ncap / 128;
      int nbmd = nrb * NSEG;
      int ngrp = (nbmd + RMD - 1) / RMD;
      k_main<<<ngrp * (RMD + RCP), 256, 0, stream>>>(Cb, Bb, normb, x, y, idx_train,
                                                     n, ncap, nbmd, N, NT, packed, out);
      k_final<<<(n + 3) / 4, 256, 0, stream>>>(x, chosen, brow, packed, N, n, interp, out);
    } else {
      k_sample<<<(n + 255) / 256, 256, 0, stream>>>(benign, n, span, k1a, k1b, k2a, k2b, mult, brow);
      k_norms<<<2 * ncap, 64, 0, stream>>>(x, chosen, brow, n, ncap, normc, normb);
      k_dist<<<(n + BM - 1) / BM, 256, 0, stream>>>(x, chosen, brow, normc, normb, n, neigh);
      k_copy<<<2048, 256, 0, stream>>>(x, y, idx_train, N, NT, n, out);
      k_newembed_int<<<n, 64, 0, stream>>>(x, chosen, brow, neigh, N, interp, out);
    }
  } else {
    k_copy<<<2048, 256, 0, stream>>>(x, y, idx_train, N, NT, n, out);
  }
}

// Round 16
// 195.142 us; speedup vs baseline: 1.0309x; 1.0309x over previous
//
#include <hip/hip_runtime.h>
#include <string.h>

#define Dims 256
#define BM 32
#define BN 32
#define KC 128
#define NSEG 16
#define BIAS 2048.0f
// interleave: groups of (RMD+RCP) blocks = RMD mdist + RCP copy (R13 tuning)
#define RMD 4
#define RCP 3

typedef float f32x4 __attribute__((ext_vector_type(4)));

// ---------- Threefry2x32 (JAX), usable host+device ----------
__host__ __device__ inline void tf2x32(unsigned k0, unsigned k1,
                                       unsigned x0, unsigned x1,
                                       unsigned* o0, unsigned* o1) {
  unsigned ks[3] = {k0, k1, k0 ^ k1 ^ 0x1BD11BDAu};
  x0 += ks[0]; x1 += ks[1];
  const unsigned rA[4] = {13u, 15u, 26u, 6u};
  const unsigned rB[4] = {17u, 29u, 16u, 24u};
#pragma unroll
  for (int g = 0; g < 5; ++g) {
    const unsigned* rr = (g & 1) ? rB : rA;
#pragma unroll
    for (int j = 0; j < 4; ++j) {
      x0 += x1;
      x1 = (x1 << rr[j]) | (x1 >> (32u - rr[j]));
      x1 ^= x0;
    }
    x0 += ks[(g + 1) % 3];
    x1 += ks[(g + 2) % 3] + (unsigned)(g + 1);
  }
  *o0 = x0; *o1 = x1;
}

// f32 -> fp8 e4m3fn (RNE, saturate, flush small to 0)
__device__ inline unsigned f2e4m3(float f) {
  unsigned u = __builtin_bit_cast(unsigned, f);
  unsigned s = (u >> 24) & 0x80u;
  int e = (int)((u >> 23) & 0xFFu) - 127;
  unsigned m = u & 0x7FFFFFu;
  if (e < -6) return s;
  unsigned mr = m + 0x7FFFFu + ((m >> 20) & 1u);
  unsigned mm;
  if (mr & 0x800000u) { mm = 0u; e += 1; } else mm = mr >> 20;
  if (e > 8) return s | 0x7Eu;
  return s | ((unsigned)(e + 7) << 3) | mm;
}

// ---------- 1a) parallel count: 64 blocks over idx_train ----------
__global__ __launch_bounds__(256) void k_count(
    const int* __restrict__ idx_train, const int* __restrict__ y, int NT,
    int ept, int* __restrict__ cnt1, int* __restrict__ cnt0) {
  int t = threadIdx.x, b = blockIdx.x;
  int base = (b * 256 + t) * ept;
  int n1 = 0, n0 = 0;
  for (int k = 0; k < ept; ++k) {
    int e = base + k;
    if (e < NT) {
      if (y[idx_train[e]] == 1) n1++; else n0++;
    }
  }
  int lane = t & 63, w = t >> 6;
#pragma unroll
  for (int d = 32; d >= 1; d >>= 1) {
    n1 += __shfl_down(n1, d, 64);
    n0 += __shfl_down(n0, d, 64);
  }
  __shared__ int s1[4], s0[4];
  if (lane == 0) { s1[w] = n1; s0[w] = n0; }
  __syncthreads();
  if (t == 0) {
    cnt1[b] = s1[0] + s1[1] + s1[2] + s1[3];
    cnt0[b] = s0[0] + s0[1] + s0[2] + s0[3];
  }
}

// ---------- 1b) stable scatter into chosen/benign ----------
__global__ __launch_bounds__(256) void k_scatter(
    const int* __restrict__ idx_train, const int* __restrict__ y, int NT,
    int ept, const int* __restrict__ cnt1, const int* __restrict__ cnt0,
    int* __restrict__ chosen, int* __restrict__ benign) {
  int t = threadIdx.x, b = blockIdx.x;
  int base1 = 0, base0 = 0;
  for (int i = 0; i < b; ++i) { base1 += cnt1[i]; base0 += cnt0[i]; }
  int base = (b * 256 + t) * ept;
  int n1 = 0, n0 = 0;
  for (int k = 0; k < ept; ++k) {
    int e = base + k;
    if (e < NT) {
      if (y[idx_train[e]] == 1) n1++; else n0++;
    }
  }
  int lane = t & 63, w = t >> 6;
  int s1v = n1, s0v = n0;
#pragma unroll
  for (int d = 1; d < 64; d <<= 1) {
    int v1 = __shfl_up(s1v, d, 64);
    int v0 = __shfl_up(s0v, d, 64);
    if (lane >= d) { s1v += v1; s0v += v0; }
  }
  __shared__ int wsum1[4], wsum0[4], woff1[4], woff0[4];
  if (lane == 63) { wsum1[w] = s1v; wsum0[w] = s0v; }
  __syncthreads();
  if (t == 0) {
    int a = 0, c = 0;
    for (int i = 0; i < 4; ++i) {
      woff1[i] = a; a += wsum1[i];
      woff0[i] = c; c += wsum0[i];
    }
  }
  __syncthreads();
  int p1 = base1 + woff1[w] + s1v - n1;
  int p0 = base0 + woff0[w] + s0v - n0;
  for (int k = 0; k < ept; ++k) {
    int e = base + k;
    if (e < NT) {
      int idx = idx_train[e];
      if (y[idx] == 1) chosen[p1++] = idx; else benign[p0++] = idx;
    }
  }
}

// ---------- 2) fused sample + gather + fp8 convert + norms + key init ----------
__global__ __launch_bounds__(256) void k_prep(
    const float* __restrict__ x, const int* __restrict__ chosen,
    const int* __restrict__ benign, int n, int ncap,
    unsigned span, unsigned k1a, unsigned k1b, unsigned k2a, unsigned k2b,
    unsigned mult, unsigned char* __restrict__ Cb, unsigned char* __restrict__ Bb,
    int* __restrict__ brow, float* __restrict__ normb,
    unsigned* __restrict__ packed) {
  int g = blockIdx.x * 4 + (threadIdx.x >> 6);
  int lane = threadIdx.x & 63;
  bool isC = (g < ncap);
  int j = isC ? g : (g - ncap);
  if (isC && lane == 0) packed[j] = 0xFFFFFFFFu;
  unsigned char* dst = (isC ? Cb : Bb) + ((size_t)j << 8) + lane * 4;
  if (j >= n) {
    *(unsigned*)dst = 0u;
    if (!isC && lane == 0) normb[j] = 3.4e38f;
    return;
  }
  int row;
  if (isC) {
    row = chosen[j];
  } else {
    unsigned a0, a1, b0, b1;
    tf2x32(k1a, k1b, 0u, (unsigned)j, &a0, &a1);
    tf2x32(k2a, k2b, 0u, (unsigned)j, &b0, &b1);
    unsigned hi = a0 ^ a1, lo = b0 ^ b1;
    unsigned r = ((hi % span) * mult + (lo % span)) % span;
    row = benign[r];
    if (lane == 0) brow[j] = row;
  }
  float4 v = ((const float4*)(x + ((size_t)row << 8)))[lane];
  unsigned p = f2e4m3(v.x) | (f2e4m3(v.y) << 8) | (f2e4m3(v.z) << 16) |
               (f2e4m3(v.w) << 24);
  *(unsigned*)dst = p;
  if (!isC) {
    float s = v.x * v.x + v.y * v.y + v.z * v.z + v.w * v.w;
#pragma unroll
    for (int m = 32; m >= 1; m >>= 1) s += __shfl_xor(s, m, 64);
    if (lane == 0) normb[j] = s;
  }
}

// ---------- 3) fused: fp8 MFMA distance+argmin + x-copy/tails, 4:3 interleaved ----------
// Best-known configuration (R13, 196us): fp8 k_main (0 bank conflicts, VGPR 68,
// MfmaUtil ~32% = the 2-barrier K-loop structure ceiling) with 4:3 dispatch
// interleave so the HBM copy streams under MFMA. R15's 4:1+NT retune: neutral.
// launch_bounds stays (256,2): raising min-blocks clamps VGPR and spills (R8/R9).
__global__ __launch_bounds__(256, 2) void k_main(
    const unsigned char* __restrict__ Cb, const unsigned char* __restrict__ Bb,
    const float* __restrict__ normb, const float* __restrict__ x,
    const int* __restrict__ y, const int* __restrict__ idx_train,
    int n, int ncap, int nbmd, int N, int NT,
    unsigned* __restrict__ packed, float* __restrict__ out) {
  const int gg = blockIdx.x / (RMD + RCP), rg = blockIdx.x % (RMD + RCP);
  if (rg >= RMD) {
    // ---- copy part: x -> out, plus y/idx tails ----
    const int cid = gg * RCP + (rg - RMD);
    const int ncb = (gridDim.x / (RMD + RCP)) * RCP;
    const size_t stride = (size_t)ncb * 256;
    const size_t total4 = (size_t)N * 64;
    const float4* __restrict__ x4 = (const float4*)x;
    float4* __restrict__ o4 = (float4*)out;
    for (size_t i = (size_t)cid * 256 + threadIdx.x; i < total4; i += stride)
      o4[i] = x4[i];
    long base2 = (long)(N + n) * Dims;
    long base3 = base2 + (N + n);
    long start = (long)cid * 256 + threadIdx.x;
    for (long k = start; k < N + n; k += stride)
      out[base2 + k] = (k < N) ? (float)y[k] : 1.0f;
    for (long k = start; k < NT + n; k += stride)
      out[base3 + k] = (k < NT) ? (float)idx_train[k] : (float)(N + (k - NT));
    return;
  }
  const int mb = gg * RMD + rg;
  if (mb >= nbmd) return;
  __shared__ __align__(16) char Bs[2][16384];
  const int tid = threadIdx.x;
  const int l = tid & 63;
  const int w = tid >> 6;
  const int lr = l & 15, lg = l >> 4;
  const int seg = mb & (NSEG - 1);       // B-segment (L2 locality per XCD)
  const int R0 = (mb / NSEG) * 128;      // 128-row blocks (wave = 32 rows)
  const int ntiles = ncap >> 6;
  const int per = (ntiles + NSEG - 1) / NSEG;
  const int t0 = seg * per;
  int t1 = t0 + per; if (t1 > ntiles) t1 = ntiles;
  if (t0 >= t1) return;

  // staging: thread owns col sc(+32), 8B chunks sq+8i
  const int sc = tid >> 3;
  const int sq = tid & 7;
  const int sqm = sq | ((sq & 1) << 3);    // f(c) for c=sq+8i (i-independent)
  const int lgm = lg | ((lg & 1) << 3);    // f(c) lane part for reads

  long sreg[4];
#define SLOADH(ct, half)                                                        \
  {                                                                             \
    const char* sb = (const char*)Bb + ((size_t)(ct) << 14) +                   \
                     (size_t)(sc + (half) * 32) * 256 + sq * 8;                 \
    _Pragma("unroll") for (int i = 0; i < 4; ++i)                               \
        sreg[i] = *(const long*)(sb + i * 64);                                  \
  }
#define SWRITEH(buf, half)                                                      \
  {                                                                             \
    char* db = Bs[buf];                                                         \
    const int colh = sc + (half) * 32;                                          \
    _Pragma("unroll") for (int i = 0; i < 4; ++i) {                             \
      const int c = sq + 8 * i;                                                 \
      const int S = ((colh >> 4) * 8 + (c >> 2)) * 64 + (c & 3) * 16 +          \
                    (colh & 15);                                                \
      *(long*)(db + ((S ^ sqm) << 3)) = sreg[i];                                \
    }                                                                           \
  }

  // prologue: stage tile t0; pull A fragments (fp8, 8B each) into regs
  SLOADH(t0, 0);
  long af[2][8];
  {
    const char* Ab = (const char*)Cb + (size_t)(R0 + w * 32 + lr) * 256 + lg * 8;
#pragma unroll
    for (int mf = 0; mf < 2; ++mf)
#pragma unroll
      for (int ko = 0; ko < 8; ++ko)
        af[mf][ko] = *(const long*)(Ab + mf * 4096 + ko * 32);
  }
  SWRITEH(0, 0);
  SLOADH(t0, 1);
  SWRITEH(0, 1);
  __syncthreads();

  unsigned key[2][4];
#pragma unroll
  for (int mf = 0; mf < 2; ++mf)
#pragma unroll
    for (int j = 0; j < 4; ++j) key[mf][j] = 0xFFFFFFFFu;

  const int rowbase = R0 + w * 32 + lg * 4;  // + mf*16 + j

  int cur = 0;
  for (int ct = t0; ct < t1; ++ct) {
    const int C0 = ct << 6;
    const bool more = (ct + 1 < t1);
    const int nxt = cur ^ 1;

    if (more) SLOADH(ct + 1, 0);   // issued first: SWRITEH waits vmcnt(4), nb stays in flight
    float nb[4];
#pragma unroll
    for (int nf = 0; nf < 4; ++nf) nb[nf] = normb[C0 + nf * 16 + lr] + BIAS;

    f32x4 acc[2][4];
#pragma unroll
    for (int mf = 0; mf < 2; ++mf)
#pragma unroll
      for (int nf = 0; nf < 4; ++nf) acc[mf][nf] = (f32x4){0.f, 0.f, 0.f, 0.f};

    const char* Bbuf = Bs[cur];
#pragma unroll
    for (int ko = 0; ko < 4; ++ko) {
      long bf[4];
#pragma unroll
      for (int nf = 0; nf < 4; ++nf)
        bf[nf] = *(const long*)(Bbuf +
            (((nf * 8 + ko) * 64 + lg * 16 + (lr ^ lgm ^ ((ko & 1) << 2))) << 3));
      __builtin_amdgcn_s_setprio(1);
#pragma unroll
      for (int mf = 0; mf < 2; ++mf)
#pragma unroll
        for (int nf = 0; nf < 4; ++nf)
          acc[mf][nf] = __builtin_amdgcn_mfma_f32_16x16x32_fp8_fp8(
              af[mf][ko], bf[nf], acc[mf][nf], 0, 0, 0);
      __builtin_amdgcn_s_setprio(0);
    }
    if (more) {
      SWRITEH(nxt, 0);
      SLOADH(ct + 1, 1);
    }
#pragma unroll
    for (int ko = 4; ko < 8; ++ko) {
      long bf[4];
#pragma unroll
      for (int nf = 0; nf < 4; ++nf)
        bf[nf] = *(const long*)(Bbuf +
            (((nf * 8 + ko) * 64 + lg * 16 + (lr ^ lgm ^ ((ko & 1) << 2))) << 3));
      __builtin_amdgcn_s_setprio(1);
#pragma unroll
      for (int mf = 0; mf < 2; ++mf)
#pragma unroll
        for (int nf = 0; nf < 4; ++nf)
          acc[mf][nf] = __builtin_amdgcn_mfma_f32_16x16x32_fp8_fp8(
              af[mf][ko], bf[nf], acc[mf][nf], 0, 0, 0);
      __builtin_amdgcn_s_setprio(0);
    }

    // epilogue: m = nb + BIAS - 2*dot (row norm dropped: argmin-invariant)
    const bool ovl = (R0 + 128 > C0) && (R0 < C0 + 64);
#pragma unroll
    for (int mf = 0; mf < 2; ++mf) {
#pragma unroll
      for (int j = 0; j < 4; ++j) {
        unsigned kmin = key[mf][j];
        const int rowg = rowbase + mf * 16 + j;
#pragma unroll
        for (int nf = 0; nf < 4; ++nf) {
          const int colg = C0 + nf * 16 + lr;
          float m = fmaf(acc[mf][nf][j], -2.0f, nb[nf]);
          unsigned q = (__builtin_bit_cast(unsigned, m) & 0xFFFFC000u) | (unsigned)colg;
          if (ovl && colg == rowg) q = 0xFFFFFFFFu;
          kmin = (q < kmin) ? q : kmin;
        }
        key[mf][j] = kmin;
      }
    }

    if (more) {
      SWRITEH(nxt, 1);
      __syncthreads();
      cur = nxt;
    }
  }
#undef SLOADH
#undef SWRITEH

#pragma unroll
  for (int mf = 0; mf < 2; ++mf) {
#pragma unroll
    for (int j = 0; j < 4; ++j) {
      unsigned k = key[mf][j];
#pragma unroll
      for (int m = 1; m < 16; m <<= 1) {
        unsigned o = __shfl_xor(k, m, 64);
        k = (o < k) ? o : k;
      }
      if (lr == 0) {
        int rowg = rowbase + mf * 16 + j;
        if (rowg < n) atomicMin(&packed[rowg], k);
      }
    }
  }
}

// ---------- 4) interpolated synthetic rows ----------
__global__ __launch_bounds__(256) void k_final(
    const float* __restrict__ x, const int* __restrict__ crow,
    const int* __restrict__ brow, const unsigned* __restrict__ packed,
    int N, int n, float interp, float* __restrict__ out) {
  int r = blockIdx.x * 4 + (threadIdx.x >> 6);
  int lane = threadIdx.x & 63;
  if (r >= n) return;
  int col = (int)(packed[r] & 0x3FFFu);
  const float4* c = (const float4*)(x + ((size_t)crow[r] << 8));
  const float4* b = (const float4*)(x + ((size_t)brow[col] << 8));
  float4 cv = c[lane], bv = b[lane];
  float4 o;
  o.x = cv.x + (bv.x - cv.x) * interp;
  o.y = cv.y + (bv.y - cv.y) * interp;
  o.z = cv.z + (bv.z - cv.z) * interp;
  o.w = cv.w + (bv.w - cv.w) * interp;
  ((float4*)(out + ((size_t)N + r) * Dims))[lane] = o;
}

// ---------- standalone copy (fallback path) ----------
__global__ __launch_bounds__(256) void k_copy(
    const float* __restrict__ x, const int* __restrict__ y,
    const int* __restrict__ idx_train, int N, int NT, int n,
    float* __restrict__ out) {
  const size_t total4 = (size_t)N * 64;
  const size_t stride = (size_t)gridDim.x * 256;
  const float4* __restrict__ x4 = (const float4*)x;
  float4* __restrict__ o4 = (float4*)out;
  for (size_t i = (size_t)blockIdx.x * 256 + threadIdx.x; i < total4; i += stride)
    o4[i] = x4[i];
  long base2 = (long)(N + n) * Dims;
  long base3 = base2 + (N + n);
  long start = (long)blockIdx.x * 256 + threadIdx.x;
  for (long k = start; k < N + n; k += stride)
    out[base2 + k] = (k < N) ? (float)y[k] : 1.0f;
  for (long k = start; k < NT + n; k += stride)
    out[base3 + k] = (k < NT) ? (float)idx_train[k] : (float)(N + (k - NT));
}

// ---------- fallback fp32 path ----------
__global__ void k_sample(const int* __restrict__ benign, int n, unsigned span,
                         unsigned k1a, unsigned k1b, unsigned k2a, unsigned k2b,
                         unsigned mult, int* __restrict__ brow) {
  int j = blockIdx.x * blockDim.x + threadIdx.x;
  if (j >= n) return;
  unsigned a0, a1, b0, b1;
  tf2x32(k1a, k1b, 0u, (unsigned)j, &a0, &a1);
  tf2x32(k2a, k2b, 0u, (unsigned)j, &b0, &b1);
  unsigned hi = a0 ^ a1, lo = b0 ^ b1;
  unsigned r = ((hi % span) * mult + (lo % span)) % span;
  brow[j] = benign[r];
}

__global__ __launch_bounds__(64) void k_norms(
    const float* __restrict__ x, const int* __restrict__ crow,
    const int* __restrict__ brow, int n, int ncap, float* __restrict__ normc,
    float* __restrict__ normb) {
  int b = blockIdx.x;
  int lane = threadIdx.x;
  bool isC = (b < ncap);
  int j = isC ? b : (b - ncap);
  if (j >= n) {
    if (lane == 0) { if (isC) normc[j] = 0.f; else normb[j] = 3.4e38f; }
    return;
  }
  int row = isC ? crow[j] : brow[j];
  float4 v = ((const float4*)(x + ((size_t)row << 8)))[lane];
  float s = v.x * v.x + v.y * v.y + v.z * v.z + v.w * v.w;
#pragma unroll
  for (int m = 32; m >= 1; m >>= 1) s += __shfl_xor(s, m, 64);
  if (lane == 0) { if (isC) normc[j] = s; else normb[j] = s; }
}

__global__ __launch_bounds__(256) void k_dist(
    const float* __restrict__ x, const int* __restrict__ crow,
    const int* __restrict__ brow, const float* __restrict__ normc,
    const float* __restrict__ normb, int n, int* __restrict__ neigh) {
  __shared__ float cs[BM][Dims + 4];
  __shared__ float bs[BN][KC + 4];
  const int tid = threadIdx.x;
  const int tx = tid & 15, ty = tid >> 4;
  const int R0 = blockIdx.x * BM;
  const int gra = R0 + ty, grb = R0 + ty + 16;
  for (int k = tid; k < BM * (Dims / 4); k += 256) {
    int r = k >> 6, i4 = k & 63;
    int gr = R0 + r;
    float4 v = make_float4(0.f, 0.f, 0.f, 0.f);
    if (gr < n) v = *(const float4*)(x + (size_t)crow[gr] * Dims + i4 * 4);
    *(float4*)(&cs[r][i4 * 4]) = v;
  }
  float nca = 0.f, ncb = 0.f;
  if (gra < n) nca = normc[gra];
  if (grb < n) ncb = normc[grb];
  float bva = 3.4e38f, bvb = 3.4e38f;
  int bia = 0, bib = 0;
  for (int C0 = 0; C0 < n; C0 += BN) {
    float a00 = 0.f, a01 = 0.f, a10 = 0.f, a11 = 0.f;
    for (int k0 = 0; k0 < Dims; k0 += KC) {
      __syncthreads();
      for (int k = tid; k < BN * (KC / 4); k += 256) {
        int c = k >> 5, i4 = k & 31;
        int gc = C0 + c;
        float4 v = make_float4(0.f, 0.f, 0.f, 0.f);
        if (gc < n) v = *(const float4*)(x + (size_t)brow[gc] * Dims + k0 + i4 * 4);
        *(float4*)(&bs[c][i4 * 4]) = v;
      }
      __syncthreads();
#pragma unroll 8
      for (int i = 0; i < KC; i += 4) {
        float4 ca = *(const float4*)(&cs[ty][k0 + i]);
        float4 cb = *(const float4*)(&cs[ty + 16][k0 + i]);
        float4 ba = *(const float4*)(&bs[tx][i]);
        float4 bb = *(const float4*)(&bs[tx + 16][i]);
        a00 += ca.x * ba.x + ca.y * ba.y + ca.z * ba.z + ca.w * ba.w;
        a01 += ca.x * bb.x + ca.y * bb.y + ca.z * bb.z + ca.w * bb.w;
        a10 += cb.x * ba.x + cb.y * ba.y + cb.z * ba.z + cb.w * ba.w;
        a11 += cb.x * bb.x + cb.y * bb.y + cb.z * bb.z + cb.w * bb.w;
      }
    }
    int gca = C0 + tx, gcb = C0 + tx + 16;
    if (gca < n) {
      float nbv = normb[gca];
      if (gra < n && gca != gra) {
        float d2 = nca + nbv - 2.f * a00;
        if (d2 < bva) { bva = d2; bia = gca; }
      }
      if (grb < n && gca != grb) {
        float d2 = ncb + nbv - 2.f * a10;
        if (d2 < bvb) { bvb = d2; bib = gca; }
      }
    }
    if (gcb < n) {
      float nbv = normb[gcb];
      if (gra < n && gcb != gra) {
        float d2 = nca + nbv - 2.f * a01;
        if (d2 < bva) { bva = d2; bia = gcb; }
      }
      if (grb < n && gcb != grb) {
        float d2 = ncb + nbv - 2.f * a11;
        if (d2 < bvb) { bvb = d2; bib = gcb; }
      }
    }
  }
#pragma unroll
  for (int m = 1; m < 16; m <<= 1) {
    float ov = __shfl_xor(bva, m, 64);
    int oi = __shfl_xor(bia, m, 64);
    if (ov < bva || (ov == bva && oi < bia)) { bva = ov; bia = oi; }
    ov = __shfl_xor(bvb, m, 64);
    oi = __shfl_xor(bib, m, 64);
    if (ov < bvb || (ov == bvb && oi < bib)) { bvb = ov; bib = oi; }
  }
  if (tx == 0) {
    if (gra < n) neigh[gra] = bia;
    if (grb < n) neigh[grb] = bib;
  }
}

__global__ __launch_bounds__(64) void k_newembed_int(
    const float* __restrict__ x, const int* __restrict__ crow,
    const int* __restrict__ brow, const int* __restrict__ neigh,
    int N, float interp, float* __restrict__ out) {
  int r = blockIdx.x;
  int lane = threadIdx.x;
  const float4* c = (const float4*)(x + (size_t)crow[r] * Dims);
  const float4* b = (const float4*)(x + (size_t)brow[neigh[r]] * Dims);
  float4 cv = c[lane], bv = b[lane];
  float4 o;
  o.x = cv.x + (bv.x - cv.x) * interp;
  o.y = cv.y + (bv.y - cv.y) * interp;
  o.z = cv.z + (bv.z - cv.z) * interp;
  o.w = cv.w + (bv.w - cv.w) * interp;
  ((float4*)(out + ((size_t)N + r) * Dims))[lane] = o;
}

extern "C" void kernel_launch(void* const* d_in, const int* in_sizes, int n_in,
                              void* d_out, int out_size, void* d_ws, size_t ws_size,
                              hipStream_t stream) {
  const float* x = (const float*)d_in[0];
  const int* y = (const int*)d_in[1];
  const int* idx_train = (const int*)d_in[2];
  float* out = (float*)d_out;
  const int N = in_sizes[1];
  const int NT = in_sizes[2];

  long nl = ((long)out_size - ((long)N * Dims + N + NT)) / (Dims + 2);
  int n = (int)nl;
  if (n < 0) n = 0;
  if (n > NT) n = NT;
  int nb = NT - n;
  int ncap = (n + 255) & ~255;
  if (ncap < 256) ncap = 256;

  size_t cap = ((size_t)NT + 255) & ~(size_t)255;
  int* chosen = (int*)d_ws;
  int* benign = chosen + cap;
  int* brow = benign + cap;
  int* neigh = brow + cap;
  float* normc = (float*)(neigh + cap);
  float* normb = normc + cap;
  unsigned* packed = (unsigned*)(normb + cap);
  unsigned char* Cb = (unsigned char*)(packed + ((ncap + 255) & ~255));
  unsigned char* Bb = Cb + (size_t)ncap * 256;
  size_t need = (char*)(Bb + (size_t)ncap * 256) - (char*)d_ws;
  bool use_mfma = (ws_size >= need) && (ncap <= 16384);
  int* cnt1 = neigh;
  int* cnt0 = neigh + 64;

  // Host-side JAX threefry derivations from key(42)
  unsigned s0_, s1_, t0_, t1_;
  tf2x32(0u, 42u, 0u, 0u, &s0_, &s1_);
  tf2x32(0u, 42u, 0u, 1u, &t0_, &t1_);
  unsigned i0_, i1_;
  tf2x32(t0_, t1_, 0u, 0u, &i0_, &i1_);
  unsigned ub = i0_ ^ i1_;
  float interp;
  { unsigned uu = (ub >> 9) | 0x3f800000u; memcpy(&interp, &uu, 4); interp -= 1.0f; }
  unsigned k1a, k1b, k2a, k2b;
  { unsigned a, b; tf2x32(s0_, s1_, 0u, 0u, &a, &b); k1a = a; k1b = b; }
  { unsigned a, b; tf2x32(s0_, s1_, 0u, 1u, &a, &b); k2a = a; k2b = b; }
  unsigned span = (nb > 0) ? (unsigned)nb : 1u;
  unsigned m0 = 65536u % span;
  unsigned mult = (m0 * m0) % span;

  int ept = (NT + 64 * 256 - 1) / (64 * 256);
  k_count<<<64, 256, 0, stream>>>(idx_train, y, NT, ept, cnt1, cnt0);
  k_scatter<<<64, 256, 0, stream>>>(idx_train, y, NT, ept, cnt1, cnt0, chosen, benign);
  if (n > 0 && nb > 0) {
    if (use_mfma) {
      k_prep<<<(2 * ncap) / 4, 256, 0, stream>>>(x, chosen, benign, n, ncap, span,
                                                 k1a, k1b, k2a, k2b, mult,
                                                 Cb, Bb, brow, normb, packed);
      int nrb = ncap / 128;
      int nbmd = nrb * NSEG;
      int ngrp = (nbmd + RMD - 1) / RMD;
      k_main<<<ngrp * (RMD + RCP), 256, 0, stream>>>(Cb, Bb, normb, x, y, idx_train,
                                                     n, ncap, nbmd, N, NT, packed, out);
      k_final<<<(n + 3) / 4, 256, 0, stream>>>(x, chosen, brow, packed, N, n, interp, out);
    } else {
      k_sample<<<(n + 255) / 256, 256, 0, stream>>>(benign, n, span, k1a, k1b, k2a, k2b, mult, brow);
      k_norms<<<2 * ncap, 64, 0, stream>>>(x, chosen, brow, n, ncap, normc, normb);
      k_dist<<<(n + BM - 1) / BM, 256, 0, stream>>>(x, chosen, brow, normc, normb, n, neigh);
      k_copy<<<2048, 256, 0, stream>>>(x, y, idx_train, N, NT, n, out);
      k_newembed_int<<<n, 64, 0, stream>>>(x, chosen, brow, neigh, N, interp, out);
    }
  } else {
    k_copy<<<2048, 256, 0, stream>>>(x, y, idx_train, N, NT, n, out);
  }
}